// Round 6
// baseline (361.404 us; speedup 1.0000x reference)
//
#include <hip/hip_runtime.h>

// Problem constants (match reference)
constexpr int S_ = 200000;   // master nodes
constexpr int N_ = 250000;   // new nodes
// L = B = 64

constexpr int NCHUNK = (N_ + 63) / 64;   // 3907
constexpr int ENC_BLOCKS = (NCHUNK + 3) / 4;  // 977, 4 chunks per block
constexpr int WEN_BLOCKS = NCHUNK * 2;        // 32-j blocks, cover + zero-fill tail
constexpr int DEC_BLOCKS = (N_ + 31) / 32;    // 7813

typedef __attribute__((ext_vector_type(8))) short bf16x8;
typedef __attribute__((ext_vector_type(4))) float f32x4;
typedef __attribute__((ext_vector_type(4))) unsigned short us4;
typedef __attribute__((ext_vector_type(8))) unsigned short us8;

// ---------------------------------------------------------------------------
// K1: added[n] = (nn_m[nn_n[n]] != n); c_m histogram (added only, over nn_n);
//     ecnt[j] = #masters with nn_m=j  +  added[j]  (extended segment size).
__global__ void k_added_counts(const int* __restrict__ nn_n, const int* __restrict__ nn_m,
                               int* __restrict__ added, int* __restrict__ c_m,
                               int* __restrict__ ecnt) {
    int i = blockIdx.x * 256 + threadIdx.x;
    if (i < N_) {
        int m = nn_n[i];
        int a = (nn_m[m] != i) ? 1 : 0;
        added[i] = a;
        if (a) {
            atomicAdd(&c_m[m], 1);
            atomicAdd(&ecnt[i], 1);
        }
    }
    if (i < S_) {
        atomicAdd(&ecnt[nn_m[i]], 1);
    }
}

// ---------------------------------------------------------------------------
// K2: per-block sums of ecnt (1024 elements / block) for the exclusive scan.
__global__ void k_scan_blocksum(const int* __restrict__ ecnt, int* __restrict__ bsum) {
    __shared__ int sd[256];
    int b = blockIdx.x, t = threadIdx.x;
    int base = b * 1024 + t * 4;
    int s = 0;
#pragma unroll
    for (int k = 0; k < 4; k++) { int idx = base + k; if (idx < N_) s += ecnt[idx]; }
    sd[t] = s;
    __syncthreads();
    for (int off = 128; off > 0; off >>= 1) {
        if (t < off) sd[t] += sd[t + off];
        __syncthreads();
    }
    if (t == 0) bsum[b] = sd[0];
}

// K3: exclusive scan -> offs.
__global__ void k_scan_apply(const int* __restrict__ ecnt, const int* __restrict__ bsum,
                             int* __restrict__ offs) {
    __shared__ int sd[256];
    __shared__ int sp[256];
    int b = blockIdx.x, t = threadIdx.x;
    sp[t] = (t < b) ? bsum[t] : 0;
    __syncthreads();
    for (int off = 128; off > 0; off >>= 1) {
        if (t < off) sp[t] += sp[t + off];
        __syncthreads();
    }
    int prev = sp[0];

    int base = b * 1024 + t * 4;
    int v[4]; int s = 0;
#pragma unroll
    for (int k = 0; k < 4; k++) { int idx = base + k; v[k] = (idx < N_) ? ecnt[idx] : 0; s += v[k]; }
    sd[t] = s;
    __syncthreads();
    for (int off = 1; off < 256; off <<= 1) {
        int xv = (t >= off) ? sd[t - off] : 0;
        __syncthreads();
        sd[t] += xv;
        __syncthreads();
    }
    int run = prev + sd[t] - s;
#pragma unroll
    for (int k = 0; k < 4; k++) {
        int idx = base + k;
        if (idx < N_) offs[idx] = run;
        run += v[k];
    }
}

// K4: extended CSR fill — masters (nn_m inverse) plus the added contributor
//     nn_n[j] appended to segment j.
__global__ void k_fill(const int* __restrict__ nn_m, const int* __restrict__ nn_n,
                       const int* __restrict__ added, const int* __restrict__ offs,
                       int* __restrict__ fill, int* __restrict__ elist) {
    int i = blockIdx.x * 256 + threadIdx.x;
    if (i < S_) {
        int j = nn_m[i];
        int p = atomicAdd(&fill[j], 1);
        elist[offs[j] + p] = i;
    }
    if (i < N_ && added[i]) {
        int p = atomicAdd(&fill[i], 1);
        elist[offs[i] + p] = nn_n[i];
    }
}

// ---------------------------------------------------------------------------
// K5: We_n[j,:] = sum_{m in elist(j)} We_m[m,:] / (c_m[m]+1).
// BRANCH-FREE 8-deep gather rounds: invalid slots clamp the elist index into
// range and clamp mm->0 (row-0 gather = wave-broadcast L1 hit); correctness
// via sc = valid ? 1/(c_m+1) : 0 (cndmask). Loads are unconditional so the
// compiler must keep 8 gathers in flight (v6's per-segment branches
// serialized them: VGPR=32 proved it).
// Block = 32 j (half chunk): wave wv owns j = b*32 + wv*8 + s.
// Epilogue: half-chunk = dense 8 KB Wf region (ch = b>>1, sH = b&1);
// per-thread acc[0..7] -> one contiguous us8 (i=s, kq2=wv) for hi and lo.
// Fully-OOB blocks write zeros (replaces tail memset).
// Wf layout (ushort): [(ch*2+sH)*4096 + ct*1024 + hl*512 + (l15+16*kq2)*8 + i]
__global__ __launch_bounds__(256) void k_wen(
        const float* __restrict__ We_m, const int* __restrict__ c_m,
        const int* __restrict__ ecnt, const int* __restrict__ offs,
        const int* __restrict__ elist, unsigned short* __restrict__ Wf) {
    __shared__ unsigned short sw[4096];       // 8 KB half-chunk image
    int t = threadIdx.x;
    int lane = t & 63;
    int wv = __builtin_amdgcn_readfirstlane(t >> 6);
    int b = blockIdx.x;
    int jb = b * 32 + wv * 8;                 // 8 segments per wave
    int c[8], o[8];
    float acc[8];
#pragma unroll
    for (int s = 0; s < 8; s++) {
        int j = jb + s;
        bool v = (j < N_);
        c[s] = v ? __builtin_amdgcn_readfirstlane(ecnt[j]) : 0;
        o[s] = v ? __builtin_amdgcn_readfirstlane(offs[j]) : 0;
        acc[s] = 0.f;
    }
    int cmax = 0;
#pragma unroll
    for (int s = 0; s < 8; s++) cmax = max(cmax, c[s]);
    for (int q = 0; q < cmax; q++) {
        int mm[8]; float sc[8];
#pragma unroll
        for (int s = 0; s < 8; s++) {
            int cl = max(c[s] - 1, 0);
            int p = o[s] + min(q, cl);                 // always in-range
            int e = __builtin_amdgcn_readfirstlane(elist[p]);
            bool valid = (q < c[s]);
            mm[s] = valid ? e : 0;                     // s_cselect, no branch
        }
#pragma unroll
        for (int s = 0; s < 8; s++) {
            int cm = __builtin_amdgcn_readfirstlane(c_m[mm[s]]);
            bool valid = (q < c[s]);
            sc[s] = valid ? 1.0f / (float)(cm + 1) : 0.0f;   // cndmask
        }
        float row[8];
#pragma unroll
        for (int s = 0; s < 8; s++)
            row[s] = We_m[(size_t)mm[s] * 64 + lane];  // 8 unconditional gathers
#pragma unroll
        for (int s = 0; s < 8; s++)
            acc[s] += row[s] * sc[s];
    }

    // ---- epilogue: hi/lo bf16 split -> one us8 run each -> LDS -> global
    int ct = lane >> 4, l15 = lane & 15;
    us8 hv, lv;
#pragma unroll
    for (int s = 0; s < 8; s++) {
        float v = acc[s];
        unsigned u = __float_as_uint(v);
        hv[s] = (unsigned short)(u >> 16);
        float r = v - __uint_as_float(u & 0xffff0000u);
        lv[s] = (unsigned short)(__float_as_uint(r) >> 16);
    }
    int base = ct * 1024 + (l15 + 16 * wv) * 8;        // kq2 = wv, i = s
    *(us8*)&sw[base]       = hv;
    *(us8*)&sw[base + 512] = lv;
    __syncthreads();
    int ch = b >> 1, sH = b & 1;
    size_t R = ((size_t)ch * 2 + sH) * 4096;
#pragma unroll
    for (int r = 0; r < 2; r++) {
        int idx = r * 2048 + t * 8;
        *(us8*)(Wf + R + idx) = *(const us8*)&sw[idx]; // 16 B coalesced
    }
}

// ---------------------------------------------------------------------------
// K6: encode GEMM z[b,l] = sum_n x[b,n]*We_n[n,l]  via MFMA.
// fp32 emulated with bf16 hi/lo split: a*b ~= ah*bh + al*bh + ah*bl.
// No LDS, no barriers. Wave wv owns rows [16wv,16wv+16) (disjoint A bands);
// A fragments load straight from x in native MFMA layout. B fragments come
// pre-split/pre-swizzled from Wf (linear lane*16B loads); shared via L1/L2.
// Epilogue: dense atomicAdd into zp2[row][b*64+l].
__global__ __launch_bounds__(256) void k_encode(const float* __restrict__ x,
        const unsigned short* __restrict__ Wf, float* __restrict__ zp2) {
    int t = threadIdx.x;
    int lane = t & 63;
    int wv = t >> 6;                 // row band
    int mrow = lane & 15;            // A row within band / C col
    int kq = lane >> 4;              // A k-quad / C row-quad
    const float* xbase = x + (size_t)(wv * 16 + mrow) * N_ + kq * 8;
    f32x4 acc[4];
#pragma unroll
    for (int ct = 0; ct < 4; ct++) acc[ct] = (f32x4){0.f, 0.f, 0.f, 0.f};

    for (int cc = 0; cc < 4; cc++) {
        int c = blockIdx.x * 4 + cc;
        if (c >= NCHUNK) break;
        int n0 = c * 64;
#pragma unroll
        for (int s = 0; s < 2; s++) {
            // ---- A raw load (8 consecutive fp32 along k), tail-guarded ----
            float av[8];
            if (n0 + s * 32 + kq * 8 + 8 <= N_) {
                float4 a0 = *(const float4*)(xbase + n0 + s * 32);
                float4 a1 = *(const float4*)(xbase + n0 + s * 32 + 4);
                av[0] = a0.x; av[1] = a0.y; av[2] = a0.z; av[3] = a0.w;
                av[4] = a1.x; av[5] = a1.y; av[6] = a1.z; av[7] = a1.w;
            } else {
#pragma unroll
                for (int i = 0; i < 8; i++) av[i] = 0.f;
            }
            // ---- B fragments: linear, coalesced, already bf16 hi/lo ----
            const bf16x8* bp = (const bf16x8*)Wf + ((size_t)c * 2 + s) * 512 + lane;
            bf16x8 bh[4], bl[4];
#pragma unroll
            for (int ct = 0; ct < 4; ct++) {
                bh[ct] = bp[ct * 128];
                bl[ct] = bp[ct * 128 + 64];
            }
            // ---- split A into hi/lo bf16 ----
            bf16x8 ah, al;
#pragma unroll
            for (int i = 0; i < 8; i++) {
                float v = av[i];
                unsigned u = __float_as_uint(v);
                ah[i] = (short)(u >> 16);
                float r = v - __uint_as_float(u & 0xffff0000u);
                al[i] = (short)(__float_as_uint(r) >> 16);
            }
            // ---- 12 MFMAs: 4 col-tiles x 3 split terms ----
#pragma unroll
            for (int ct = 0; ct < 4; ct++) {
                acc[ct] = __builtin_amdgcn_mfma_f32_16x16x32_bf16(ah, bh[ct], acc[ct], 0, 0, 0);
                acc[ct] = __builtin_amdgcn_mfma_f32_16x16x32_bf16(al, bh[ct], acc[ct], 0, 0, 0);
                acc[ct] = __builtin_amdgcn_mfma_f32_16x16x32_bf16(ah, bl[ct], acc[ct], 0, 0, 0);
            }
        }
    }

    // Epilogue: C/D layout col=lane&15, row=(lane>>4)*4+reg (verified m89).
    int row = blockIdx.x & 63;
    float* zr = zp2 + row * 4096;
#pragma unroll
    for (int ct = 0; ct < 4; ct++) {
#pragma unroll
        for (int r = 0; r < 4; r++) {
            int b = wv * 16 + kq * 4 + r;
            int l = ct * 16 + mrow;
            atomicAdd(&zr[b * 64 + l], acc[ct][r]);   // 16 consecutive floats/quad
        }
    }
}

// K7: z2g[l*64+b] = sum_rows zp2[b*64+l] + be[l].  (zp2 is b-major)
__global__ void k_zred(const float* __restrict__ zp2, const float* __restrict__ be_m,
                       float* __restrict__ z2g) {
    int slot = blockIdx.x * 256 + threadIdx.x;   // 16 blocks x 256, slot = b*64+l
    float s = 0.f;
    for (int r = 0; r < 64; r++) s += zp2[r * 4096 + slot];
    int b = slot >> 6, l = slot & 63;
    z2g[l * 64 + b] = s + be_m[l];
}

// ---------------------------------------------------------------------------
// K8: P[m,b] = sum_l z2g[l*64+b] * Wd_m[l,m] + bd_m[m].  P layout [S][64].
// Live accumulator is acc[16]. Block = 64-m tile; wave bg owns b in
// [bg*16, bg*16+16); lane = m. Wd tile staged in LDS (coalesced float4);
// inner read ws[l*64+m] 64-consecutive -> 2-way alias (free). z2g slice
// wave-uniform -> s_load_dwordx16 per l, pipelined via unroll.
__global__ __launch_bounds__(256) void k_pmat(
        const float* __restrict__ Wd_m, const float* __restrict__ bd_m,
        const float* __restrict__ z2g, float* __restrict__ P) {
    __shared__ float ws[64 * 64];
    int t = threadIdx.x;
    int m0 = blockIdx.x * 64;
    // stage Wd_m[l][m0:m0+64] tile: 4 float4 loads per thread, coalesced
#pragma unroll
    for (int r = 0; r < 4; r++) {
        int flat = r * 256 + t;          // 0..1023
        int l = flat >> 4;               // 0..63
        int c4 = flat & 15;              // 0..15
        float4 v = *(const float4*)&Wd_m[(size_t)l * S_ + m0 + c4 * 4];
        *(float4*)&ws[l * 64 + c4 * 4] = v;
    }
    __syncthreads();

    int m = t & 63;
    int bg = __builtin_amdgcn_readfirstlane(t >> 6);   // wave-uniform b-group
    float bd = bd_m[m0 + m];
    float acc[16];
#pragma unroll
    for (int q = 0; q < 16; q++) acc[q] = bd;
    const float* zb = z2g + bg * 16;
#pragma unroll 4
    for (int l = 0; l < 64; l++) {
        float w = ws[l * 64 + m];
        const float* zr = zb + l * 64;   // wave-uniform -> s_load_dwordx16
#pragma unroll
        for (int q = 0; q < 16; q++) acc[q] += w * zr[q];
    }

    float4* Pv = (float4*)&P[(size_t)(m0 + m) * 64 + bg * 16];
#pragma unroll
    for (int q4 = 0; q4 < 4; q4++)
        Pv[q4] = make_float4(acc[q4 * 4 + 0], acc[q4 * 4 + 1],
                             acc[q4 * 4 + 2], acc[q4 * 4 + 3]);
}

// ---------------------------------------------------------------------------
// K9: out[b,j] = (sum_{m in elist(j)} P[m,b]) / max(ecnt[j],1).
// Same branch-free 8-deep gather structure as k_wen: 32-j block, wave owns
// 8 segments, unconditional clamped gathers, sc in {0,1} multiply.
// lane = b; 32-j tile through LDS for coalesced out writes.
__global__ __launch_bounds__(256) void k_decode(const float* __restrict__ P,
        const int* __restrict__ ecnt, const int* __restrict__ offs,
        const int* __restrict__ elist, float* __restrict__ out) {
    __shared__ float tile[32][65];
    int t = threadIdx.x;
    int wv = __builtin_amdgcn_readfirstlane(t >> 6);
    int lane = t & 63;
    int j0 = blockIdx.x * 32;
    int jb = j0 + wv * 8;
    int c[8], o[8];
    float acc[8];
#pragma unroll
    for (int s = 0; s < 8; s++) {
        int j = jb + s;
        bool v = (j < N_);
        c[s] = v ? __builtin_amdgcn_readfirstlane(ecnt[j]) : 0;
        o[s] = v ? __builtin_amdgcn_readfirstlane(offs[j]) : 0;
        acc[s] = 0.f;
    }
    int cmax = 0;
#pragma unroll
    for (int s = 0; s < 8; s++) cmax = max(cmax, c[s]);
    for (int q = 0; q < cmax; q++) {
        int mm[8]; float sc[8];
#pragma unroll
        for (int s = 0; s < 8; s++) {
            int cl = max(c[s] - 1, 0);
            int p = o[s] + min(q, cl);
            int e = __builtin_amdgcn_readfirstlane(elist[p]);
            bool valid = (q < c[s]);
            mm[s] = valid ? e : 0;
            sc[s] = valid ? 1.0f : 0.0f;
        }
        float row[8];
#pragma unroll
        for (int s = 0; s < 8; s++)
            row[s] = P[(size_t)mm[s] * 64 + lane];     // 8 unconditional gathers
#pragma unroll
        for (int s = 0; s < 8; s++)
            acc[s] += row[s] * sc[s];
    }
#pragma unroll
    for (int s = 0; s < 8; s++) {
        int cc = (c[s] > 1) ? c[s] : 1;
        tile[wv * 8 + s][lane] = acc[s] * (1.0f / (float)cc);
    }
    __syncthreads();
#pragma unroll
    for (int r = 0; r < 8; r++) {
        int b = r * 8 + (t >> 5);
        int j = j0 + (t & 31);
        if (j < N_) out[(size_t)b * N_ + j] = tile[t & 31][b];
    }
}

// ---------------------------------------------------------------------------
extern "C" void kernel_launch(void* const* d_in, const int* in_sizes, int n_in,
                              void* d_out, int out_size, void* d_ws, size_t ws_size,
                              hipStream_t stream) {
    const float* We_m = (const float*)d_in[0];
    const float* be_m = (const float*)d_in[1];
    const float* Wd_m = (const float*)d_in[2];
    const float* bd_m = (const float*)d_in[3];
    const float* x    = (const float*)d_in[4];
    const int*   nn_n = (const int*)d_in[5];
    const int*   nn_m = (const int*)d_in[6];
    float* out = (float*)d_out;
    char* ws = (char*)d_ws;

    // Workspace layout (byte offsets). Region 0 holds Wf (pre-split bf16
    // We_n fragments, 3907*16384 = 64,012,288 B) during the encode phase,
    // then is reused for P [S,64] (51.2 MB) in the decode phase.
    unsigned short* Wf = (unsigned short*)(ws + 0);
    float* P     = (float*)(ws + 0);           // aliases Wf; phase-ordered
    int*   c_m   = (int*)(ws + 64012288);      //    800,000 B (zeroed)
    int*   ecnt  = (int*)(ws + 64812288);      //  1,000,000 B (zeroed)
    int*   fill  = (int*)(ws + 65812288);      //  1,000,000 B (zeroed)
    int*   added = (int*)(ws + 66812288);      //  1,000,000 B
    int*   offs  = (int*)(ws + 67812288);      //  1,000,000 B
    int*   elist = (int*)(ws + 68812288);      //  2,000,000 B (<= (S+N)*4 = 1.8 MB)
    float* zp2   = (float*)(ws + 70812288);    //  1,048,576 B (64 x 4096, zeroed)
    float* z2g   = (float*)(ws + 71860864);    //     16,384 B
    int*   bsum  = (int*)(ws + 71877248);      //      1,024 B
    // total ~71.9 MB

    hipMemsetAsync(ws + 64012288, 0, 2800000, stream);       // c_m, ecnt, fill
    hipMemsetAsync(zp2, 0, 1048576, stream);                 // zp2

    k_added_counts<<<977, 256, 0, stream>>>(nn_n, nn_m, added, c_m, ecnt);
    k_scan_blocksum<<<245, 256, 0, stream>>>(ecnt, bsum);
    k_scan_apply<<<245, 256, 0, stream>>>(ecnt, bsum, offs);
    k_fill<<<977, 256, 0, stream>>>(nn_m, nn_n, added, offs, fill, elist);
    k_wen<<<WEN_BLOCKS, 256, 0, stream>>>(We_m, c_m, ecnt, offs, elist, Wf);
    k_encode<<<ENC_BLOCKS, 256, 0, stream>>>(x, Wf, zp2);
    k_zred<<<16, 256, 0, stream>>>(zp2, be_m, z2g);
    k_pmat<<<3125, 256, 0, stream>>>(Wd_m, bd_m, z2g, P);
    k_decode<<<DEC_BLOCKS, 256, 0, stream>>>(P, ecnt, offs, elist, out);
}

// Round 7
// 350.699 us; speedup vs baseline: 1.0305x; 1.0305x over previous
//
#include <hip/hip_runtime.h>

// Problem constants (match reference)
constexpr int S_ = 200000;   // master nodes
constexpr int N_ = 250000;   // new nodes
// L = B = 64

constexpr int NCHUNK = (N_ + 63) / 64;   // 3907
constexpr int ENC_BLOCKS = (NCHUNK + 3) / 4;  // 977, 4 chunks per block
constexpr int WEN_BLOCKS = NCHUNK * 2;        // 32-j blocks, cover + zero-fill tail
constexpr int DEC_BLOCKS = (N_ + 31) / 32;    // 7813

constexpr int EMASK = 0x3FFFF;                // low 18 bits: master index

typedef __attribute__((ext_vector_type(8))) short bf16x8;
typedef __attribute__((ext_vector_type(4))) float f32x4;
typedef __attribute__((ext_vector_type(4))) unsigned short us4;
typedef __attribute__((ext_vector_type(8))) unsigned short us8;

// ---------------------------------------------------------------------------
// K1: added[n] = (nn_m[nn_n[n]] != n); c_m histogram (added only, over nn_n);
//     ecnt[j] = #masters with nn_m=j  +  added[j]  (extended segment size).
__global__ void k_added_counts(const int* __restrict__ nn_n, const int* __restrict__ nn_m,
                               int* __restrict__ added, int* __restrict__ c_m,
                               int* __restrict__ ecnt) {
    int i = blockIdx.x * 256 + threadIdx.x;
    if (i < N_) {
        int m = nn_n[i];
        int a = (nn_m[m] != i) ? 1 : 0;
        added[i] = a;
        if (a) {
            atomicAdd(&c_m[m], 1);
            atomicAdd(&ecnt[i], 1);
        }
    }
    if (i < S_) {
        atomicAdd(&ecnt[nn_m[i]], 1);
    }
}

// ---------------------------------------------------------------------------
// K2: per-block sums of ecnt (1024 elements / block) for the exclusive scan.
__global__ void k_scan_blocksum(const int* __restrict__ ecnt, int* __restrict__ bsum) {
    __shared__ int sd[256];
    int b = blockIdx.x, t = threadIdx.x;
    int base = b * 1024 + t * 4;
    int s = 0;
#pragma unroll
    for (int k = 0; k < 4; k++) { int idx = base + k; if (idx < N_) s += ecnt[idx]; }
    sd[t] = s;
    __syncthreads();
    for (int off = 128; off > 0; off >>= 1) {
        if (t < off) sd[t] += sd[t + off];
        __syncthreads();
    }
    if (t == 0) bsum[b] = sd[0];
}

// K3: exclusive scan -> offs.
__global__ void k_scan_apply(const int* __restrict__ ecnt, const int* __restrict__ bsum,
                             int* __restrict__ offs) {
    __shared__ int sd[256];
    __shared__ int sp[256];
    int b = blockIdx.x, t = threadIdx.x;
    sp[t] = (t < b) ? bsum[t] : 0;
    __syncthreads();
    for (int off = 128; off > 0; off >>= 1) {
        if (t < off) sp[t] += sp[t + off];
        __syncthreads();
    }
    int prev = sp[0];

    int base = b * 1024 + t * 4;
    int v[4]; int s = 0;
#pragma unroll
    for (int k = 0; k < 4; k++) { int idx = base + k; v[k] = (idx < N_) ? ecnt[idx] : 0; s += v[k]; }
    sd[t] = s;
    __syncthreads();
    for (int off = 1; off < 256; off <<= 1) {
        int xv = (t >= off) ? sd[t - off] : 0;
        __syncthreads();
        sd[t] += xv;
        __syncthreads();
    }
    int run = prev + sd[t] - s;
#pragma unroll
    for (int k = 0; k < 4; k++) {
        int idx = base + k;
        if (idx < N_) offs[idx] = run;
        run += v[k];
    }
}

// K4: extended CSR fill — masters (nn_m inverse) plus the added contributor
//     nn_n[j] appended to segment j. Entries are PACKED: m | (c_m[m] << 18)
//     (m < 2^18; c_m max ~15), so k_wen's round loop needs no dependent
//     c_m load (its 2-deep SMEM chain was the wall: SMEM is unordered ->
//     every use is a full lgkmcnt drain). c_m (0.8 MB) is L2-resident here.
__global__ void k_fill(const int* __restrict__ nn_m, const int* __restrict__ nn_n,
                       const int* __restrict__ added, const int* __restrict__ offs,
                       const int* __restrict__ c_m,
                       int* __restrict__ fill, int* __restrict__ elist) {
    int i = blockIdx.x * 256 + threadIdx.x;
    if (i < S_) {
        int j = nn_m[i];
        int p = atomicAdd(&fill[j], 1);
        elist[offs[j] + p] = i | (c_m[i] << 18);        // coalesced c_m read
    }
    if (i < N_ && added[i]) {
        int m = nn_n[i];
        int p = atomicAdd(&fill[i], 1);
        elist[offs[i] + p] = m | (c_m[m] << 18);        // random, L2-resident
    }
}

// ---------------------------------------------------------------------------
// K5: We_n[j,:] = sum_{m in elist(j)} We_m[m,:] / (c_m[m]+1).
// Branch-free 8-deep gather rounds; scale comes PACKED in the elist entry
// (no dependent scalar load). elist reads are rotate-prefetched one round
// ahead so the compiler's wait-at-use lands where the loads have had a full
// round (gather latency) to complete.
// Block = 32 j (half chunk): wave wv owns j = b*32 + wv*8 + s.
// Epilogue: half-chunk = dense 8 KB Wf region (ch = b>>1, sH = b&1);
// per-thread acc[0..7] -> one contiguous us8 (i=s, kq2=wv) for hi and lo.
// Fully-OOB blocks write zeros (replaces tail memset).
// Wf layout (ushort): [(ch*2+sH)*4096 + ct*1024 + hl*512 + (l15+16*kq2)*8 + i]
__global__ __launch_bounds__(256) void k_wen(
        const float* __restrict__ We_m,
        const int* __restrict__ ecnt, const int* __restrict__ offs,
        const int* __restrict__ elist, unsigned short* __restrict__ Wf) {
    __shared__ unsigned short sw[4096];       // 8 KB half-chunk image
    int t = threadIdx.x;
    int lane = t & 63;
    int wv = __builtin_amdgcn_readfirstlane(t >> 6);
    int b = blockIdx.x;
    int jb = b * 32 + wv * 8;                 // 8 segments per wave
    int c[8], o[8], cl[8];
    float acc[8];
#pragma unroll
    for (int s = 0; s < 8; s++) {
        int j = jb + s;
        bool v = (j < N_);
        c[s] = v ? __builtin_amdgcn_readfirstlane(ecnt[j]) : 0;
        o[s] = v ? __builtin_amdgcn_readfirstlane(offs[j]) : 0;
        cl[s] = max(c[s] - 1, 0);
        acc[s] = 0.f;
    }
    int cmax = 0;
#pragma unroll
    for (int s = 0; s < 8; s++) cmax = max(cmax, c[s]);

    if (cmax > 0) {
        int e[8];
#pragma unroll
        for (int s = 0; s < 8; s++)
            e[s] = __builtin_amdgcn_readfirstlane(elist[o[s]]);   // q=0
        for (int q = 0; q < cmax; q++) {
            int en[8];
#pragma unroll
            for (int s = 0; s < 8; s++) {
                int p = o[s] + min(q + 1, cl[s]);                 // q+1 prefetch
                en[s] = __builtin_amdgcn_readfirstlane(elist[p]);
            }
            int mm[8]; float sc[8];
#pragma unroll
            for (int s = 0; s < 8; s++) {
                bool valid = (q < c[s]);
                mm[s] = valid ? (e[s] & EMASK) : 0;               // cselect
                float r = __builtin_amdgcn_rcpf((float)((e[s] >> 18) + 1));
                sc[s] = valid ? r : 0.0f;                          // cndmask
            }
            float row[8];
#pragma unroll
            for (int s = 0; s < 8; s++)
                row[s] = We_m[(size_t)mm[s] * 64 + lane];  // 8 gathers in flight
#pragma unroll
            for (int s = 0; s < 8; s++)
                acc[s] += row[s] * sc[s];
#pragma unroll
            for (int s = 0; s < 8; s++) e[s] = en[s];
        }
    }

    // ---- epilogue: hi/lo bf16 split -> one us8 run each -> LDS -> global
    int ct = lane >> 4, l15 = lane & 15;
    us8 hv, lv;
#pragma unroll
    for (int s = 0; s < 8; s++) {
        float v = acc[s];
        unsigned u = __float_as_uint(v);
        hv[s] = (unsigned short)(u >> 16);
        float r = v - __uint_as_float(u & 0xffff0000u);
        lv[s] = (unsigned short)(__float_as_uint(r) >> 16);
    }
    int base = ct * 1024 + (l15 + 16 * wv) * 8;        // kq2 = wv, i = s
    *(us8*)&sw[base]       = hv;
    *(us8*)&sw[base + 512] = lv;
    __syncthreads();
    int ch = b >> 1, sH = b & 1;
    size_t R = ((size_t)ch * 2 + sH) * 4096;
#pragma unroll
    for (int r = 0; r < 2; r++) {
        int idx = r * 2048 + t * 8;
        *(us8*)(Wf + R + idx) = *(const us8*)&sw[idx]; // 16 B coalesced
    }
}

// ---------------------------------------------------------------------------
// K6: encode GEMM z[b,l] = sum_n x[b,n]*We_n[n,l]  via MFMA.
// fp32 emulated with bf16 hi/lo split: a*b ~= ah*bh + al*bh + ah*bl.
// No LDS, no barriers. Wave wv owns rows [16wv,16wv+16) (disjoint A bands);
// A fragments load straight from x in native MFMA layout. B fragments come
// pre-split/pre-swizzled from Wf (linear lane*16B loads); shared via L1/L2.
// Epilogue: dense atomicAdd into zp2[row][b*64+l].
__global__ __launch_bounds__(256) void k_encode(const float* __restrict__ x,
        const unsigned short* __restrict__ Wf, float* __restrict__ zp2) {
    int t = threadIdx.x;
    int lane = t & 63;
    int wv = t >> 6;                 // row band
    int mrow = lane & 15;            // A row within band / C col
    int kq = lane >> 4;              // A k-quad / C row-quad
    const float* xbase = x + (size_t)(wv * 16 + mrow) * N_ + kq * 8;
    f32x4 acc[4];
#pragma unroll
    for (int ct = 0; ct < 4; ct++) acc[ct] = (f32x4){0.f, 0.f, 0.f, 0.f};

    for (int cc = 0; cc < 4; cc++) {
        int c = blockIdx.x * 4 + cc;
        if (c >= NCHUNK) break;
        int n0 = c * 64;
#pragma unroll
        for (int s = 0; s < 2; s++) {
            // ---- A raw load (8 consecutive fp32 along k), tail-guarded ----
            float av[8];
            if (n0 + s * 32 + kq * 8 + 8 <= N_) {
                float4 a0 = *(const float4*)(xbase + n0 + s * 32);
                float4 a1 = *(const float4*)(xbase + n0 + s * 32 + 4);
                av[0] = a0.x; av[1] = a0.y; av[2] = a0.z; av[3] = a0.w;
                av[4] = a1.x; av[5] = a1.y; av[6] = a1.z; av[7] = a1.w;
            } else {
#pragma unroll
                for (int i = 0; i < 8; i++) av[i] = 0.f;
            }
            // ---- B fragments: linear, coalesced, already bf16 hi/lo ----
            const bf16x8* bp = (const bf16x8*)Wf + ((size_t)c * 2 + s) * 512 + lane;
            bf16x8 bh[4], bl[4];
#pragma unroll
            for (int ct = 0; ct < 4; ct++) {
                bh[ct] = bp[ct * 128];
                bl[ct] = bp[ct * 128 + 64];
            }
            // ---- split A into hi/lo bf16 ----
            bf16x8 ah, al;
#pragma unroll
            for (int i = 0; i < 8; i++) {
                float v = av[i];
                unsigned u = __float_as_uint(v);
                ah[i] = (short)(u >> 16);
                float r = v - __uint_as_float(u & 0xffff0000u);
                al[i] = (short)(__float_as_uint(r) >> 16);
            }
            // ---- 12 MFMAs: 4 col-tiles x 3 split terms ----
#pragma unroll
            for (int ct = 0; ct < 4; ct++) {
                acc[ct] = __builtin_amdgcn_mfma_f32_16x16x32_bf16(ah, bh[ct], acc[ct], 0, 0, 0);
                acc[ct] = __builtin_amdgcn_mfma_f32_16x16x32_bf16(al, bh[ct], acc[ct], 0, 0, 0);
                acc[ct] = __builtin_amdgcn_mfma_f32_16x16x32_bf16(ah, bl[ct], acc[ct], 0, 0, 0);
            }
        }
    }

    // Epilogue: C/D layout col=lane&15, row=(lane>>4)*4+reg (verified m89).
    int row = blockIdx.x & 63;
    float* zr = zp2 + row * 4096;
#pragma unroll
    for (int ct = 0; ct < 4; ct++) {
#pragma unroll
        for (int r = 0; r < 4; r++) {
            int b = wv * 16 + kq * 4 + r;
            int l = ct * 16 + mrow;
            atomicAdd(&zr[b * 64 + l], acc[ct][r]);   // 16 consecutive floats/quad
        }
    }
}

// K7: z2g[l*64+b] = sum_rows zp2[b*64+l] + be[l].  (zp2 is b-major)
__global__ void k_zred(const float* __restrict__ zp2, const float* __restrict__ be_m,
                       float* __restrict__ z2g) {
    int slot = blockIdx.x * 256 + threadIdx.x;   // 16 blocks x 256, slot = b*64+l
    float s = 0.f;
    for (int r = 0; r < 64; r++) s += zp2[r * 4096 + slot];
    int b = slot >> 6, l = slot & 63;
    z2g[l * 64 + b] = s + be_m[l];
}

// ---------------------------------------------------------------------------
// K8: P[m,b] = sum_l z2g[l*64+b] * Wd_m[l,m] + bd_m[m].  P layout [S][64].
// Live accumulator is acc[16]. Block = 64-m tile; wave bg owns b in
// [bg*16, bg*16+16); lane = m. Wd tile staged in LDS (coalesced float4);
// inner read ws[l*64+m] 64-consecutive -> 2-way alias (free). z2g slice
// wave-uniform -> s_load_dwordx16 per l, pipelined via unroll.
__global__ __launch_bounds__(256) void k_pmat(
        const float* __restrict__ Wd_m, const float* __restrict__ bd_m,
        const float* __restrict__ z2g, float* __restrict__ P) {
    __shared__ float ws[64 * 64];
    int t = threadIdx.x;
    int m0 = blockIdx.x * 64;
    // stage Wd_m[l][m0:m0+64] tile: 4 float4 loads per thread, coalesced
#pragma unroll
    for (int r = 0; r < 4; r++) {
        int flat = r * 256 + t;          // 0..1023
        int l = flat >> 4;               // 0..63
        int c4 = flat & 15;              // 0..15
        float4 v = *(const float4*)&Wd_m[(size_t)l * S_ + m0 + c4 * 4];
        *(float4*)&ws[l * 64 + c4 * 4] = v;
    }
    __syncthreads();

    int m = t & 63;
    int bg = __builtin_amdgcn_readfirstlane(t >> 6);   // wave-uniform b-group
    float bd = bd_m[m0 + m];
    float acc[16];
#pragma unroll
    for (int q = 0; q < 16; q++) acc[q] = bd;
    const float* zb = z2g + bg * 16;
#pragma unroll 4
    for (int l = 0; l < 64; l++) {
        float w = ws[l * 64 + m];
        const float* zr = zb + l * 64;   // wave-uniform -> s_load_dwordx16
#pragma unroll
        for (int q = 0; q < 16; q++) acc[q] += w * zr[q];
    }

    float4* Pv = (float4*)&P[(size_t)(m0 + m) * 64 + bg * 16];
#pragma unroll
    for (int q4 = 0; q4 < 4; q4++)
        Pv[q4] = make_float4(acc[q4 * 4 + 0], acc[q4 * 4 + 1],
                             acc[q4 * 4 + 2], acc[q4 * 4 + 3]);
}

// ---------------------------------------------------------------------------
// K9: out[b,j] = (sum_{m in elist(j)} P[m,b]) / max(ecnt[j],1).
// Same branch-free 8-deep structure as k_wen, with the same rotate-prefetch
// of (packed) elist entries. lane = b; 32-j tile through LDS for coalesced
// out writes.
__global__ __launch_bounds__(256) void k_decode(const float* __restrict__ P,
        const int* __restrict__ ecnt, const int* __restrict__ offs,
        const int* __restrict__ elist, float* __restrict__ out) {
    __shared__ float tile[32][65];
    int t = threadIdx.x;
    int wv = __builtin_amdgcn_readfirstlane(t >> 6);
    int lane = t & 63;
    int j0 = blockIdx.x * 32;
    int jb = j0 + wv * 8;
    int c[8], o[8], cl[8];
    float acc[8];
#pragma unroll
    for (int s = 0; s < 8; s++) {
        int j = jb + s;
        bool v = (j < N_);
        c[s] = v ? __builtin_amdgcn_readfirstlane(ecnt[j]) : 0;
        o[s] = v ? __builtin_amdgcn_readfirstlane(offs[j]) : 0;
        cl[s] = max(c[s] - 1, 0);
        acc[s] = 0.f;
    }
    int cmax = 0;
#pragma unroll
    for (int s = 0; s < 8; s++) cmax = max(cmax, c[s]);

    if (cmax > 0) {
        int e[8];
#pragma unroll
        for (int s = 0; s < 8; s++)
            e[s] = __builtin_amdgcn_readfirstlane(elist[o[s]]);
        for (int q = 0; q < cmax; q++) {
            int en[8];
#pragma unroll
            for (int s = 0; s < 8; s++) {
                int p = o[s] + min(q + 1, cl[s]);
                en[s] = __builtin_amdgcn_readfirstlane(elist[p]);
            }
            int mm[8]; float sc[8];
#pragma unroll
            for (int s = 0; s < 8; s++) {
                bool valid = (q < c[s]);
                mm[s] = valid ? (e[s] & EMASK) : 0;
                sc[s] = valid ? 1.0f : 0.0f;
            }
            float row[8];
#pragma unroll
            for (int s = 0; s < 8; s++)
                row[s] = P[(size_t)mm[s] * 64 + lane];     // 8 gathers in flight
#pragma unroll
            for (int s = 0; s < 8; s++)
                acc[s] += row[s] * sc[s];
#pragma unroll
            for (int s = 0; s < 8; s++) e[s] = en[s];
        }
    }
#pragma unroll
    for (int s = 0; s < 8; s++) {
        int cc = (c[s] > 1) ? c[s] : 1;
        tile[wv * 8 + s][lane] = acc[s] * (1.0f / (float)cc);
    }
    __syncthreads();
#pragma unroll
    for (int r = 0; r < 8; r++) {
        int b = r * 8 + (t >> 5);
        int j = j0 + (t & 31);
        if (j < N_) out[(size_t)b * N_ + j] = tile[t & 31][b];
    }
}

// ---------------------------------------------------------------------------
extern "C" void kernel_launch(void* const* d_in, const int* in_sizes, int n_in,
                              void* d_out, int out_size, void* d_ws, size_t ws_size,
                              hipStream_t stream) {
    const float* We_m = (const float*)d_in[0];
    const float* be_m = (const float*)d_in[1];
    const float* Wd_m = (const float*)d_in[2];
    const float* bd_m = (const float*)d_in[3];
    const float* x    = (const float*)d_in[4];
    const int*   nn_n = (const int*)d_in[5];
    const int*   nn_m = (const int*)d_in[6];
    float* out = (float*)d_out;
    char* ws = (char*)d_ws;

    // Workspace layout (byte offsets). Region 0 holds Wf (pre-split bf16
    // We_n fragments, 3907*16384 = 64,012,288 B) during the encode phase,
    // then is reused for P [S,64] (51.2 MB) in the decode phase.
    unsigned short* Wf = (unsigned short*)(ws + 0);
    float* P     = (float*)(ws + 0);           // aliases Wf; phase-ordered
    int*   c_m   = (int*)(ws + 64012288);      //    800,000 B (zeroed)
    int*   ecnt  = (int*)(ws + 64812288);      //  1,000,000 B (zeroed)
    int*   fill  = (int*)(ws + 65812288);      //  1,000,000 B (zeroed)
    int*   added = (int*)(ws + 66812288);      //  1,000,000 B
    int*   offs  = (int*)(ws + 67812288);      //  1,000,000 B
    int*   elist = (int*)(ws + 68812288);      //  2,000,000 B (<= (S+N)*4 = 1.8 MB)
    float* zp2   = (float*)(ws + 70812288);    //  1,048,576 B (64 x 4096, zeroed)
    float* z2g   = (float*)(ws + 71860864);    //     16,384 B
    int*   bsum  = (int*)(ws + 71877248);      //      1,024 B
    // total ~71.9 MB

    hipMemsetAsync(ws + 64012288, 0, 2800000, stream);       // c_m, ecnt, fill
    hipMemsetAsync(zp2, 0, 1048576, stream);                 // zp2

    k_added_counts<<<977, 256, 0, stream>>>(nn_n, nn_m, added, c_m, ecnt);
    k_scan_blocksum<<<245, 256, 0, stream>>>(ecnt, bsum);
    k_scan_apply<<<245, 256, 0, stream>>>(ecnt, bsum, offs);
    k_fill<<<977, 256, 0, stream>>>(nn_m, nn_n, added, offs, c_m, fill, elist);
    k_wen<<<WEN_BLOCKS, 256, 0, stream>>>(We_m, ecnt, offs, elist, Wf);
    k_encode<<<ENC_BLOCKS, 256, 0, stream>>>(x, Wf, zp2);
    k_zred<<<16, 256, 0, stream>>>(zp2, be_m, z2g);
    k_pmat<<<3125, 256, 0, stream>>>(Wd_m, bd_m, z2g, P);
    k_decode<<<DEC_BLOCKS, 256, 0, stream>>>(P, ecnt, offs, elist, out);
}

// Round 8
// 331.134 us; speedup vs baseline: 1.0914x; 1.0591x over previous
//
#include <hip/hip_runtime.h>

// Problem constants (match reference)
constexpr int S_ = 200000;   // master nodes
constexpr int N_ = 250000;   // new nodes
// L = B = 64

constexpr int NCHUNK = (N_ + 63) / 64;        // 3907
constexpr int FUSE_BLOCKS = (NCHUNK + 1) / 2; // 1954, 2 chunks per block
constexpr int DEC_BLOCKS = (N_ + 31) / 32;    // 7813

constexpr int EMASK = 0x3FFFF;                // low 18 bits: master index

typedef __attribute__((ext_vector_type(8))) short bf16x8;
typedef __attribute__((ext_vector_type(4))) float f32x4;
typedef __attribute__((ext_vector_type(8))) unsigned short us8;

// ---------------------------------------------------------------------------
// K1: added[n] = (nn_m[nn_n[n]] != n); c_m histogram (added only, over nn_n);
//     ecnt[j] = #masters with nn_m=j  +  added[j]  (extended segment size).
__global__ void k_added_counts(const int* __restrict__ nn_n, const int* __restrict__ nn_m,
                               int* __restrict__ added, int* __restrict__ c_m,
                               int* __restrict__ ecnt) {
    int i = blockIdx.x * 256 + threadIdx.x;
    if (i < N_) {
        int m = nn_n[i];
        int a = (nn_m[m] != i) ? 1 : 0;
        added[i] = a;
        if (a) {
            atomicAdd(&c_m[m], 1);
            atomicAdd(&ecnt[i], 1);
        }
    }
    if (i < S_) {
        atomicAdd(&ecnt[nn_m[i]], 1);
    }
}

// ---------------------------------------------------------------------------
// K2: per-block sums of ecnt (1024 elements / block) for the exclusive scan.
__global__ void k_scan_blocksum(const int* __restrict__ ecnt, int* __restrict__ bsum) {
    __shared__ int sd[256];
    int b = blockIdx.x, t = threadIdx.x;
    int base = b * 1024 + t * 4;
    int s = 0;
#pragma unroll
    for (int k = 0; k < 4; k++) { int idx = base + k; if (idx < N_) s += ecnt[idx]; }
    sd[t] = s;
    __syncthreads();
    for (int off = 128; off > 0; off >>= 1) {
        if (t < off) sd[t] += sd[t + off];
        __syncthreads();
    }
    if (t == 0) bsum[b] = sd[0];
}

// K3: exclusive scan -> offs.
__global__ void k_scan_apply(const int* __restrict__ ecnt, const int* __restrict__ bsum,
                             int* __restrict__ offs) {
    __shared__ int sd[256];
    __shared__ int sp[256];
    int b = blockIdx.x, t = threadIdx.x;
    sp[t] = (t < b) ? bsum[t] : 0;
    __syncthreads();
    for (int off = 128; off > 0; off >>= 1) {
        if (t < off) sp[t] += sp[t + off];
        __syncthreads();
    }
    int prev = sp[0];

    int base = b * 1024 + t * 4;
    int v[4]; int s = 0;
#pragma unroll
    for (int k = 0; k < 4; k++) { int idx = base + k; v[k] = (idx < N_) ? ecnt[idx] : 0; s += v[k]; }
    sd[t] = s;
    __syncthreads();
    for (int off = 1; off < 256; off <<= 1) {
        int xv = (t >= off) ? sd[t - off] : 0;
        __syncthreads();
        sd[t] += xv;
        __syncthreads();
    }
    int run = prev + sd[t] - s;
#pragma unroll
    for (int k = 0; k < 4; k++) {
        int idx = base + k;
        if (idx < N_) offs[idx] = run;
        run += v[k];
    }
}

// K4: extended CSR fill — masters (nn_m inverse) plus the added contributor
//     nn_n[j] appended to segment j. Entries PACKED: m | (c_m[m] << 18)
//     (m < 2^18; c_m max ~15) so gather loops need no dependent c_m load.
__global__ void k_fill(const int* __restrict__ nn_m, const int* __restrict__ nn_n,
                       const int* __restrict__ added, const int* __restrict__ offs,
                       const int* __restrict__ c_m,
                       int* __restrict__ fill, int* __restrict__ elist) {
    int i = blockIdx.x * 256 + threadIdx.x;
    if (i < S_) {
        int j = nn_m[i];
        int p = atomicAdd(&fill[j], 1);
        elist[offs[j] + p] = i | (c_m[i] << 18);        // coalesced c_m read
    }
    if (i < N_ && added[i]) {
        int m = nn_n[i];
        int p = atomicAdd(&fill[i], 1);
        elist[offs[i] + p] = m | (c_m[m] << 18);        // random, L2-resident
    }
}

// ---------------------------------------------------------------------------
// K5 (FUSED k_wen + k_encode): per chunk of 64 j's,
//   phase G: We_n[j,:] = sum_{m in elist(j)} We_m[m,:] * rcp(c_m+1)
//            (branch-free 8-deep rounds, packed elist, rotate-prefetch;
//             wave wv owns j = n0 + wv*16 + g*8 + s, g=0,1);
//            hi/lo bf16 split written to a 16 KB LDS fragment image
//            sw[sH*4096 + ct*1024 + hl*512 + (l15+16*kq2)*8 + i]
//            with sH=wv>>1, kq2=(wv&1)*2+g, i=s  (each slot written once).
//   phase M: encode MFMA z[b,l] += x[b,n]*We_n[n,l], fp32 emulated by
//            bf16 hi/lo (ah*bh + al*bh + ah*bl); A straight from x in
//            native fragment layout, B via ds_read_b128 from sw.
// Rationale: k_wen was at the L3 random-gather BW wall with idle VALU/MFMA;
// k_encode was latency-bound with idle memory. Fusion overlaps them across
// blocks and deletes the 62.5 MB Wf write + read-back entirely.
// Epilogue: dense atomicAdd into zp2[row][b*64+l], row = blockIdx & 63.
__global__ __launch_bounds__(256) void k_wenc(
        const float* __restrict__ x, const float* __restrict__ We_m,
        const int* __restrict__ ecnt, const int* __restrict__ offs,
        const int* __restrict__ elist, float* __restrict__ zp2) {
    __shared__ unsigned short sw[8192];   // 16 KB fragment image (one chunk)
    int t = threadIdx.x;
    int lane = t & 63;
    int wv = __builtin_amdgcn_readfirstlane(t >> 6);
    int mrow = lane & 15;                 // A row within band / C col
    int kq = lane >> 4;                   // A k-quad / C row-quad
    int ct = lane >> 4, l15 = lane & 15;  // gather-epilogue coords
    const float* xbase = x + (size_t)(wv * 16 + mrow) * N_ + kq * 8;
    f32x4 acc[4];
#pragma unroll
    for (int i = 0; i < 4; i++) acc[i] = (f32x4){0.f, 0.f, 0.f, 0.f};

    for (int cc = 0; cc < 2; cc++) {
        int chk = blockIdx.x * 2 + cc;
        if (chk >= NCHUNK) break;         // block-uniform
        int n0 = chk * 64;

        __syncthreads();                  // prior MFMA phase done reading sw
        // ---------------- phase G: two 8-segment gather groups ----------------
        for (int g = 0; g < 2; g++) {
            int jb = n0 + wv * 16 + g * 8;
            int c[8], o[8], cl[8];
            float ag[8];
#pragma unroll
            for (int s = 0; s < 8; s++) {
                int j = jb + s;
                bool v = (j < N_);
                c[s] = v ? __builtin_amdgcn_readfirstlane(ecnt[j]) : 0;
                o[s] = v ? __builtin_amdgcn_readfirstlane(offs[j]) : 0;
                cl[s] = max(c[s] - 1, 0);
                ag[s] = 0.f;
            }
            int cmax = 0;
#pragma unroll
            for (int s = 0; s < 8; s++) cmax = max(cmax, c[s]);
            if (cmax > 0) {
                int e[8];
#pragma unroll
                for (int s = 0; s < 8; s++)
                    e[s] = __builtin_amdgcn_readfirstlane(elist[o[s]]);
                for (int q = 0; q < cmax; q++) {
                    int en[8];
#pragma unroll
                    for (int s = 0; s < 8; s++) {
                        int p = o[s] + min(q + 1, cl[s]);
                        en[s] = __builtin_amdgcn_readfirstlane(elist[p]);
                    }
                    int mm[8]; float sc[8];
#pragma unroll
                    for (int s = 0; s < 8; s++) {
                        bool valid = (q < c[s]);
                        mm[s] = valid ? (e[s] & EMASK) : 0;
                        float r = __builtin_amdgcn_rcpf((float)((e[s] >> 18) + 1));
                        sc[s] = valid ? r : 0.0f;
                    }
                    float row[8];
#pragma unroll
                    for (int s = 0; s < 8; s++)
                        row[s] = We_m[(size_t)mm[s] * 64 + lane];
#pragma unroll
                    for (int s = 0; s < 8; s++)
                        ag[s] += row[s] * sc[s];
#pragma unroll
                    for (int s = 0; s < 8; s++) e[s] = en[s];
                }
            }
            // group epilogue: hi/lo split -> one contiguous us8 each
            us8 hv, lv;
#pragma unroll
            for (int s = 0; s < 8; s++) {
                float v = ag[s];
                unsigned u = __float_as_uint(v);
                hv[s] = (unsigned short)(u >> 16);
                float r = v - __uint_as_float(u & 0xffff0000u);
                lv[s] = (unsigned short)(__float_as_uint(r) >> 16);
            }
            int kq2 = (wv & 1) * 2 + g;
            int sH = wv >> 1;
            int base = sH * 4096 + ct * 1024 + (l15 + 16 * kq2) * 8;
            *(us8*)&sw[base]       = hv;
            *(us8*)&sw[base + 512] = lv;
        }
        __syncthreads();                  // fragment image complete

        // ---------------- phase M: MFMA over the chunk ----------------
#pragma unroll
        for (int s = 0; s < 2; s++) {
            // A raw load (8 consecutive fp32 along k), tail-guarded
            float av[8];
            if (n0 + s * 32 + kq * 8 + 8 <= N_) {
                float4 a0 = *(const float4*)(xbase + n0 + s * 32);
                float4 a1 = *(const float4*)(xbase + n0 + s * 32 + 4);
                av[0] = a0.x; av[1] = a0.y; av[2] = a0.z; av[3] = a0.w;
                av[4] = a1.x; av[5] = a1.y; av[6] = a1.z; av[7] = a1.w;
            } else {
#pragma unroll
                for (int i = 0; i < 8; i++) av[i] = 0.f;
            }
            // B fragments from LDS (contiguous b128, conflict-free)
            bf16x8 bh[4], bl[4];
#pragma unroll
            for (int c2 = 0; c2 < 4; c2++) {
                bh[c2] = *(const bf16x8*)&sw[s * 4096 + c2 * 1024 + lane * 8];
                bl[c2] = *(const bf16x8*)&sw[s * 4096 + c2 * 1024 + 512 + lane * 8];
            }
            // split A into hi/lo bf16
            bf16x8 ah, al;
#pragma unroll
            for (int i = 0; i < 8; i++) {
                float v = av[i];
                unsigned u = __float_as_uint(v);
                ah[i] = (short)(u >> 16);
                float r = v - __uint_as_float(u & 0xffff0000u);
                al[i] = (short)(__float_as_uint(r) >> 16);
            }
            // 12 MFMAs: 4 col-tiles x 3 split terms
#pragma unroll
            for (int c2 = 0; c2 < 4; c2++) {
                acc[c2] = __builtin_amdgcn_mfma_f32_16x16x32_bf16(ah, bh[c2], acc[c2], 0, 0, 0);
                acc[c2] = __builtin_amdgcn_mfma_f32_16x16x32_bf16(al, bh[c2], acc[c2], 0, 0, 0);
                acc[c2] = __builtin_amdgcn_mfma_f32_16x16x32_bf16(ah, bl[c2], acc[c2], 0, 0, 0);
            }
        }
    }

    // Epilogue: C/D layout col=lane&15, row=(lane>>4)*4+reg (verified m89).
    int row = blockIdx.x & 63;
    float* zr = zp2 + row * 4096;
#pragma unroll
    for (int c2 = 0; c2 < 4; c2++) {
#pragma unroll
        for (int r = 0; r < 4; r++) {
            int b = wv * 16 + kq * 4 + r;
            int l = c2 * 16 + mrow;
            atomicAdd(&zr[b * 64 + l], acc[c2][r]);   // 16 consecutive floats/quad
        }
    }
}

// K7: z2g[l*64+b] = sum_rows zp2[b*64+l] + be[l].  (zp2 is b-major)
__global__ void k_zred(const float* __restrict__ zp2, const float* __restrict__ be_m,
                       float* __restrict__ z2g) {
    int slot = blockIdx.x * 256 + threadIdx.x;   // 16 blocks x 256, slot = b*64+l
    float s = 0.f;
    for (int r = 0; r < 64; r++) s += zp2[r * 4096 + slot];
    int b = slot >> 6, l = slot & 63;
    z2g[l * 64 + b] = s + be_m[l];
}

// ---------------------------------------------------------------------------
// K8: P[m,b] = sum_l z2g[l*64+b] * Wd_m[l,m] + bd_m[m].  P layout [S][64].
// Live accumulator is acc[16]. Block = 64-m tile; wave bg owns b in
// [bg*16, bg*16+16); lane = m. Wd tile staged in LDS (coalesced float4);
// inner read ws[l*64+m] 64-consecutive -> 2-way alias (free). z2g slice
// wave-uniform -> s_load_dwordx16 per l, pipelined via unroll.
__global__ __launch_bounds__(256) void k_pmat(
        const float* __restrict__ Wd_m, const float* __restrict__ bd_m,
        const float* __restrict__ z2g, float* __restrict__ P) {
    __shared__ float ws[64 * 64];
    int t = threadIdx.x;
    int m0 = blockIdx.x * 64;
    // stage Wd_m[l][m0:m0+64] tile: 4 float4 loads per thread, coalesced
#pragma unroll
    for (int r = 0; r < 4; r++) {
        int flat = r * 256 + t;          // 0..1023
        int l = flat >> 4;               // 0..63
        int c4 = flat & 15;              // 0..15
        float4 v = *(const float4*)&Wd_m[(size_t)l * S_ + m0 + c4 * 4];
        *(float4*)&ws[l * 64 + c4 * 4] = v;
    }
    __syncthreads();

    int m = t & 63;
    int bg = __builtin_amdgcn_readfirstlane(t >> 6);   // wave-uniform b-group
    float bd = bd_m[m0 + m];
    float acc[16];
#pragma unroll
    for (int q = 0; q < 16; q++) acc[q] = bd;
    const float* zb = z2g + bg * 16;
#pragma unroll 4
    for (int l = 0; l < 64; l++) {
        float w = ws[l * 64 + m];
        const float* zr = zb + l * 64;   // wave-uniform -> s_load_dwordx16
#pragma unroll
        for (int q = 0; q < 16; q++) acc[q] += w * zr[q];
    }

    float4* Pv = (float4*)&P[(size_t)(m0 + m) * 64 + bg * 16];
#pragma unroll
    for (int q4 = 0; q4 < 4; q4++)
        Pv[q4] = make_float4(acc[q4 * 4 + 0], acc[q4 * 4 + 1],
                             acc[q4 * 4 + 2], acc[q4 * 4 + 3]);
}

// ---------------------------------------------------------------------------
// K9: out[b,j] = (sum_{m in elist(j)} P[m,b]) / max(ecnt[j],1).
// Branch-free 8-deep structure with rotate-prefetch of packed elist entries.
// lane = b; 32-j tile through LDS for coalesced out writes.
__global__ __launch_bounds__(256) void k_decode(const float* __restrict__ P,
        const int* __restrict__ ecnt, const int* __restrict__ offs,
        const int* __restrict__ elist, float* __restrict__ out) {
    __shared__ float tile[32][65];
    int t = threadIdx.x;
    int wv = __builtin_amdgcn_readfirstlane(t >> 6);
    int lane = t & 63;
    int j0 = blockIdx.x * 32;
    int jb = j0 + wv * 8;
    int c[8], o[8], cl[8];
    float acc[8];
#pragma unroll
    for (int s = 0; s < 8; s++) {
        int j = jb + s;
        bool v = (j < N_);
        c[s] = v ? __builtin_amdgcn_readfirstlane(ecnt[j]) : 0;
        o[s] = v ? __builtin_amdgcn_readfirstlane(offs[j]) : 0;
        cl[s] = max(c[s] - 1, 0);
        acc[s] = 0.f;
    }
    int cmax = 0;
#pragma unroll
    for (int s = 0; s < 8; s++) cmax = max(cmax, c[s]);

    if (cmax > 0) {
        int e[8];
#pragma unroll
        for (int s = 0; s < 8; s++)
            e[s] = __builtin_amdgcn_readfirstlane(elist[o[s]]);
        for (int q = 0; q < cmax; q++) {
            int en[8];
#pragma unroll
            for (int s = 0; s < 8; s++) {
                int p = o[s] + min(q + 1, cl[s]);
                en[s] = __builtin_amdgcn_readfirstlane(elist[p]);
            }
            int mm[8]; float sc[8];
#pragma unroll
            for (int s = 0; s < 8; s++) {
                bool valid = (q < c[s]);
                mm[s] = valid ? (e[s] & EMASK) : 0;
                sc[s] = valid ? 1.0f : 0.0f;
            }
            float row[8];
#pragma unroll
            for (int s = 0; s < 8; s++)
                row[s] = P[(size_t)mm[s] * 64 + lane];     // 8 gathers in flight
#pragma unroll
            for (int s = 0; s < 8; s++)
                acc[s] += row[s] * sc[s];
#pragma unroll
            for (int s = 0; s < 8; s++) e[s] = en[s];
        }
    }
#pragma unroll
    for (int s = 0; s < 8; s++) {
        int cc = (c[s] > 1) ? c[s] : 1;
        tile[wv * 8 + s][lane] = acc[s] * (1.0f / (float)cc);
    }
    __syncthreads();
#pragma unroll
    for (int r = 0; r < 8; r++) {
        int b = r * 8 + (t >> 5);
        int j = j0 + (t & 31);
        if (j < N_) out[(size_t)b * N_ + j] = tile[t & 31][b];
    }
}

// ---------------------------------------------------------------------------
extern "C" void kernel_launch(void* const* d_in, const int* in_sizes, int n_in,
                              void* d_out, int out_size, void* d_ws, size_t ws_size,
                              hipStream_t stream) {
    const float* We_m = (const float*)d_in[0];
    const float* be_m = (const float*)d_in[1];
    const float* Wd_m = (const float*)d_in[2];
    const float* bd_m = (const float*)d_in[3];
    const float* x    = (const float*)d_in[4];
    const int*   nn_n = (const int*)d_in[5];
    const int*   nn_m = (const int*)d_in[6];
    float* out = (float*)d_out;
    char* ws = (char*)d_ws;

    // Workspace layout (byte offsets). Region 0 holds P [S,64] (51.2 MB)
    // for the decode phase (the Wf staging buffer is gone — fused away).
    float* P     = (float*)(ws + 0);
    int*   c_m   = (int*)(ws + 64012288);      //    800,000 B (zeroed)
    int*   ecnt  = (int*)(ws + 64812288);      //  1,000,000 B (zeroed)
    int*   fill  = (int*)(ws + 65812288);      //  1,000,000 B (zeroed)
    int*   added = (int*)(ws + 66812288);      //  1,000,000 B
    int*   offs  = (int*)(ws + 67812288);      //  1,000,000 B
    int*   elist = (int*)(ws + 68812288);      //  2,000,000 B (<= (S+N)*4 = 1.8 MB)
    float* zp2   = (float*)(ws + 70812288);    //  1,048,576 B (64 x 4096, zeroed)
    float* z2g   = (float*)(ws + 71860864);    //     16,384 B
    int*   bsum  = (int*)(ws + 71877248);      //      1,024 B
    // total ~71.9 MB

    hipMemsetAsync(ws + 64012288, 0, 2800000, stream);       // c_m, ecnt, fill
    hipMemsetAsync(zp2, 0, 1048576, stream);                 // zp2

    k_added_counts<<<977, 256, 0, stream>>>(nn_n, nn_m, added, c_m, ecnt);
    k_scan_blocksum<<<245, 256, 0, stream>>>(ecnt, bsum);
    k_scan_apply<<<245, 256, 0, stream>>>(ecnt, bsum, offs);
    k_fill<<<977, 256, 0, stream>>>(nn_m, nn_n, added, offs, c_m, fill, elist);
    k_wenc<<<FUSE_BLOCKS, 256, 0, stream>>>(x, We_m, ecnt, offs, elist, zp2);
    k_zred<<<16, 256, 0, stream>>>(zp2, be_m, z2g);
    k_pmat<<<3125, 256, 0, stream>>>(Wd_m, bd_m, z2g, P);
    k_decode<<<DEC_BLOCKS, 256, 0, stream>>>(P, ecnt, offs, elist, out);
}